// Round 1
// baseline (802.210 us; speedup 1.0000x reference)
//
#include <hip/hip_runtime.h>

#define NTOK  49
#define CDIM  192
#define NHEAD 6
#define NWIN  1024
#define SCALE 0.17677669529663687f

// LDS layout (bytes)
#define LDS_XB 0        // [64][200] ushort  (x bf16, later reused as attn-out "ob")
#define LDS_QB 25600    // [64][200] ushort
#define LDS_KB 51200    // [64][200] ushort
#define LDS_VT 76800    // [192][72] ushort  (v transposed: [chan][token])
#define LDS_P  104448   // [2][64][72] ushort (P tiles for the 2 concurrent heads)
#define LDS_MS 122880   // [2401] float (mask window)
#define SMEM_BYTES (122880 + 9604)

typedef __bf16 bfx8 __attribute__((ext_vector_type(8)));
typedef float  f32x4 __attribute__((ext_vector_type(4)));

__device__ __forceinline__ unsigned short f2bf(float f) {
    unsigned int u = __builtin_bit_cast(unsigned int, f);
    u += 0x7fffu + ((u >> 16) & 1u);
    return (unsigned short)(u >> 16);
}

extern "C" __global__ void wattn_prep(const float* __restrict__ qkv_w,
                                      const float* __restrict__ proj_w,
                                      const float* __restrict__ rpb,
                                      const int*   __restrict__ rel,
                                      unsigned short* __restrict__ W1,
                                      unsigned short* __restrict__ W2,
                                      float* __restrict__ biasH)
{
    const int i = blockIdx.x * 256 + threadIdx.x;
    if (i < 576 * 192) W1[i] = f2bf(qkv_w[i]);
    if (i < 192 * 192) W2[i] = f2bf(proj_w[i]);
    if (i < NHEAD * NTOK * NTOK) {
        const int h  = i / (NTOK * NTOK);
        const int ij = i % (NTOK * NTOK);
        biasH[i] = rpb[rel[ij] * NHEAD + h];
    }
}

extern "C" __global__ void __launch_bounds__(512, 1)
wattn_fused(const float* __restrict__ x,
            const float* __restrict__ mask,
            const float* __restrict__ qkv_b,
            const float* __restrict__ proj_b,
            const unsigned short* __restrict__ W1,
            const unsigned short* __restrict__ W2,
            const float* __restrict__ biasH,
            float* __restrict__ out)
{
    extern __shared__ char smem[];
    unsigned short* xb = (unsigned short*)(smem + LDS_XB);
    unsigned short* qb = (unsigned short*)(smem + LDS_QB);
    unsigned short* kb = (unsigned short*)(smem + LDS_KB);
    unsigned short* vT = (unsigned short*)(smem + LDS_VT);
    unsigned short* Pl = (unsigned short*)(smem + LDS_P);
    float*          msk = (float*)(smem + LDS_MS);

    const int b    = blockIdx.x;
    const int tid  = threadIdx.x;
    const int wave = tid >> 6;
    const int lane = tid & 63;
    const int g    = lane >> 4;   // 16-lane group
    const int jn   = lane & 15;

    // ---- stage: zero x pad rows (49..63), copy mask window, x -> bf16 LDS ----
    {
        unsigned int* z = (unsigned int*)(xb + 49 * 200);
        for (int i = tid; i < 15 * 100; i += 512) z[i] = 0u;
        const float* mw = mask + (size_t)(b & (NWIN - 1)) * (NTOK * NTOK);
        for (int i = tid; i < NTOK * NTOK; i += 512) msk[i] = mw[i];
        const float4* xw = (const float4*)(x + (size_t)b * NTOK * CDIM);
        for (int i = tid; i < NTOK * CDIM / 4; i += 512) {
            float4 v = xw[i];
            unsigned int lo = (unsigned int)f2bf(v.x) | ((unsigned int)f2bf(v.y) << 16);
            unsigned int hi = (unsigned int)f2bf(v.z) | ((unsigned int)f2bf(v.w) << 16);
            unsigned int* d = (unsigned int*)(xb + (i / 48) * 200 + (i % 48) * 4);
            d[0] = lo; d[1] = hi;
        }
    }
    __syncthreads();

    // ---- qkv GEMM: out[t][o] = sum_c x[t][c] * qkv_w[o][c] + qkv_b[o] ----
    // jobs: 18 col-pair jobs (32 output cols each), 4 row-tiles per job
    for (int job = wave; job < 18; job += 8) {
        const int c0 = job * 32 + jn;  // col of sub-tile 0 for this lane
        f32x4 acc0[4], acc1[4];
        const float bv0 = qkv_b[c0];
        const float bv1 = qkv_b[c0 + 16];
#pragma unroll
        for (int mt = 0; mt < 4; ++mt) {
            acc0[mt] = (f32x4){bv0, bv0, bv0, bv0};
            acc1[mt] = (f32x4){bv1, bv1, bv1, bv1};
        }
#pragma unroll
        for (int kk = 0; kk < 6; ++kk) {
            const int ko = kk * 32 + g * 8;
            bfx8 b0 = *(const bfx8*)(W1 + (size_t)c0 * 192 + ko);
            bfx8 b1 = *(const bfx8*)(W1 + (size_t)(c0 + 16) * 192 + ko);
#pragma unroll
            for (int mt = 0; mt < 4; ++mt) {
                bfx8 a = *(const bfx8*)(xb + (mt * 16 + jn) * 200 + ko);
                acc0[mt] = __builtin_amdgcn_mfma_f32_16x16x32_bf16(a, b0, acc0[mt], 0, 0, 0);
                acc1[mt] = __builtin_amdgcn_mfma_f32_16x16x32_bf16(a, b1, acc1[mt], 0, 0, 0);
            }
        }
#pragma unroll
        for (int mt = 0; mt < 4; ++mt) {
#pragma unroll
            for (int r = 0; r < 4; ++r) {
                const int row = mt * 16 + g * 4 + r;
                const int col0 = job * 32 + jn;
                unsigned short v0 = f2bf(acc0[mt][r]);
                unsigned short v1 = f2bf(acc1[mt][r]);
                // job*32 never straddles the 192-boundaries, so branch is uniform
                if (col0 < 192) {
                    qb[row * 200 + col0] = v0;
                    qb[row * 200 + col0 + 16] = v1;
                } else if (col0 < 384) {
                    kb[row * 200 + (col0 - 192)] = v0;
                    kb[row * 200 + (col0 - 192) + 16] = v1;
                } else {
                    vT[(col0 - 384) * 72 + row] = v0;
                    vT[(col0 - 384 + 16) * 72 + row] = v1;
                }
            }
        }
    }
    __syncthreads();

    // ---- attention: 3 passes x 2 heads; wave = (hp, mt) ----
    const int mt = wave & 3;
    const int hp = wave >> 2;
    unsigned short* Ph = Pl + hp * (64 * 72);

    for (int ph = 0; ph < 3; ++ph) {
        const int h = ph * 2 + hp;
        // S = (q @ k^T)
        f32x4 s[4];
        {
            bfx8 aq = *(const bfx8*)(qb + (mt * 16 + jn) * 200 + h * 32 + g * 8);
#pragma unroll
            for (int nt = 0; nt < 4; ++nt) {
                bfx8 bk = *(const bfx8*)(kb + (nt * 16 + jn) * 200 + h * 32 + g * 8);
                f32x4 z = {0.f, 0.f, 0.f, 0.f};
                s[nt] = __builtin_amdgcn_mfma_f32_16x16x32_bf16(aq, bk, z, 0, 0, 0);
            }
        }
        // logits + wave-parallel softmax (rows live in 16-lane groups x 4 regs)
        float p[4][4];
        float m4[4], sum4[4];
#pragma unroll
        for (int nt = 0; nt < 4; ++nt)
#pragma unroll
            for (int r = 0; r < 4; ++r) {
                const int i = mt * 16 + g * 4 + r;
                const int j = nt * 16 + jn;
                float v;
                if (i < NTOK && j < NTOK)
                    v = s[nt][r] * SCALE + biasH[h * (NTOK * NTOK) + i * NTOK + j] + msk[i * NTOK + j];
                else
                    v = -1e30f;
                p[nt][r] = v;
            }
#pragma unroll
        for (int r = 0; r < 4; ++r)
            m4[r] = fmaxf(fmaxf(p[0][r], p[1][r]), fmaxf(p[2][r], p[3][r]));
#pragma unroll
        for (int d = 1; d < 16; d <<= 1)
#pragma unroll
            for (int r = 0; r < 4; ++r) m4[r] = fmaxf(m4[r], __shfl_xor(m4[r], d));
#pragma unroll
        for (int r = 0; r < 4; ++r) sum4[r] = 0.f;
#pragma unroll
        for (int nt = 0; nt < 4; ++nt)
#pragma unroll
            for (int r = 0; r < 4; ++r) {
                p[nt][r] = __expf(p[nt][r] - m4[r]);
                sum4[r] += p[nt][r];
            }
#pragma unroll
        for (int d = 1; d < 16; d <<= 1)
#pragma unroll
            for (int r = 0; r < 4; ++r) sum4[r] += __shfl_xor(sum4[r], d);
        float inv_rs[4];
#pragma unroll
        for (int r = 0; r < 4; ++r) inv_rs[r] = sum4[r] > 0.f ? 1.f / sum4[r] : 0.f;
        // store unnormalized P (bf16)
#pragma unroll
        for (int nt = 0; nt < 4; ++nt)
#pragma unroll
            for (int r = 0; r < 4; ++r)
                Ph[(mt * 16 + g * 4 + r) * 72 + nt * 16 + jn] = f2bf(p[nt][r]);
        __syncthreads();
        // O = P @ v  (A = P from LDS, B = vT rows = channels, contiguous tokens)
        f32x4 o0 = {0.f, 0.f, 0.f, 0.f}, o1 = {0.f, 0.f, 0.f, 0.f};
#pragma unroll
        for (int ks = 0; ks < 2; ++ks) {
            bfx8 ap = *(const bfx8*)(Ph + (mt * 16 + jn) * 72 + ks * 32 + g * 8);
            bfx8 bv0 = *(const bfx8*)(vT + (h * 32 + jn) * 72 + ks * 32 + g * 8);
            bfx8 bv1 = *(const bfx8*)(vT + (h * 32 + 16 + jn) * 72 + ks * 32 + g * 8);
            o0 = __builtin_amdgcn_mfma_f32_16x16x32_bf16(ap, bv0, o0, 0, 0, 0);
            o1 = __builtin_amdgcn_mfma_f32_16x16x32_bf16(ap, bv1, o1, 0, 0, 0);
        }
#pragma unroll
        for (int r = 0; r < 4; ++r) {
            const int row = mt * 16 + g * 4 + r;
            xb[row * 200 + h * 32 + jn]      = f2bf(o0[r] * inv_rs[r]);
            xb[row * 200 + h * 32 + 16 + jn] = f2bf(o1[r] * inv_rs[r]);
        }
        __syncthreads();
    }

    // ---- proj GEMM: out[t][c] = sum_k ob[t][k] * proj_w[c][k] + proj_b[c] ----
    for (int nt = wave; nt < 12; nt += 8) {
        f32x4 acc[4];
        const float pb = proj_b[nt * 16 + jn];
#pragma unroll
        for (int m = 0; m < 4; ++m) acc[m] = (f32x4){pb, pb, pb, pb};
#pragma unroll
        for (int kk = 0; kk < 6; ++kk) {
            const int ko = kk * 32 + g * 8;
            bfx8 bw = *(const bfx8*)(W2 + (size_t)(nt * 16 + jn) * 192 + ko);
#pragma unroll
            for (int m = 0; m < 4; ++m) {
                bfx8 ao = *(const bfx8*)(xb + (m * 16 + jn) * 200 + ko);
                acc[m] = __builtin_amdgcn_mfma_f32_16x16x32_bf16(ao, bw, acc[m], 0, 0, 0);
            }
        }
#pragma unroll
        for (int m = 0; m < 4; ++m)
#pragma unroll
            for (int r = 0; r < 4; ++r) {
                const int row = m * 16 + g * 4 + r;
                if (row < NTOK)
                    out[(size_t)b * (NTOK * CDIM) + row * CDIM + nt * 16 + jn] = acc[m][r];
            }
    }
}

extern "C" void kernel_launch(void* const* d_in, const int* in_sizes, int n_in,
                              void* d_out, int out_size, void* d_ws, size_t ws_size,
                              hipStream_t stream) {
    const float* x      = (const float*)d_in[0];
    const float* mask   = (const float*)d_in[1];
    const float* qkv_w  = (const float*)d_in[2];
    const float* qkv_b  = (const float*)d_in[3];
    const float* proj_w = (const float*)d_in[4];
    const float* proj_b = (const float*)d_in[5];
    const float* rpb    = (const float*)d_in[6];
    const int*   rel    = (const int*)d_in[7];
    float* outp = (float*)d_out;

    char* ws = (char*)d_ws;
    unsigned short* W1 = (unsigned short*)ws;                    // 576*192 bf16 = 221184 B
    unsigned short* W2 = (unsigned short*)(ws + 221184);         // 192*192 bf16 = 73728 B
    float* biasH       = (float*)(ws + 221184 + 73728);          // 6*2401 f32 = 57624 B

    hipFuncSetAttribute((const void*)wattn_fused,
                        hipFuncAttributeMaxDynamicSharedMemorySize, SMEM_BYTES);

    wattn_prep<<<432, 256, 0, stream>>>(qkv_w, proj_w, rpb, rel, W1, W2, biasH);
    wattn_fused<<<8192, 512, SMEM_BYTES, stream>>>(x, mask, qkv_b, proj_b, W1, W2, biasH, outp);
}